// Round 1
// baseline (156.313 us; speedup 1.0000x reference)
//
#include <hip/hip_runtime.h>

// Problem constants (from reference)
#define S 4
#define T 512
#define B 16
#define D 512
#define L (T * D)            // 262144 floats per (b,s) signal
#define SSTRIDE (T * B * D)  // 4194304 floats between sources (both tensors)

#define CHUNKS 64
#define THREADS 256
#define VEC_PER_CHUNK (L / 4 / CHUNKS)   // 65536/64 = 1024 float4 per chunk
#define ITERS (VEC_PER_CHUNK / THREADS)  // 4 iterations per thread

// preds: [S,T,B,D] -> idx = s*SSTRIDE + t*(B*D) + b*D + d
// gts:   [S,B,T,D] -> idx = s*SSTRIDE + b*L + (t*D + d)
//
// ws layout per batch b (24 floats): [0..15] dot[s_p*4+s_g], [16..19] pn[s], [20..23] gn[s]

__global__ __launch_bounds__(THREADS) void partial_kernel(
    const float* __restrict__ preds, const float* __restrict__ gts,
    float* __restrict__ ws) {
  const int b = blockIdx.x & (B - 1);
  const int chunk = blockIdx.x >> 4;
  const int tid = threadIdx.x;

  float dot[16], pn[4], gn[4];
#pragma unroll
  for (int k = 0; k < 16; k++) dot[k] = 0.f;
#pragma unroll
  for (int k = 0; k < 4; k++) { pn[k] = 0.f; gn[k] = 0.f; }

  for (int it = 0; it < ITERS; ++it) {
    const int ivec = chunk * VEC_PER_CHUNK + it * THREADS + tid;
    const int i = ivec * 4;           // element index within L
    const int t = i >> 9;             // i / 512
    const int d = i & 511;            // i % 512

    const float4* pp =
        reinterpret_cast<const float4*>(preds + (size_t)t * (B * D) + (size_t)b * D + d);
    const float4* gp = reinterpret_cast<const float4*>(gts + (size_t)b * L + i);

    float4 p[4], g[4];
#pragma unroll
    for (int s = 0; s < 4; s++) p[s] = pp[s * (SSTRIDE / 4)];
#pragma unroll
    for (int s = 0; s < 4; s++) g[s] = gp[s * (SSTRIDE / 4)];

#pragma unroll
    for (int s = 0; s < 4; s++) {
      pn[s] += p[s].x * p[s].x + p[s].y * p[s].y + p[s].z * p[s].z + p[s].w * p[s].w;
      gn[s] += g[s].x * g[s].x + g[s].y * g[s].y + g[s].z * g[s].z + g[s].w * g[s].w;
    }
#pragma unroll
    for (int sp = 0; sp < 4; sp++) {
#pragma unroll
      for (int sg = 0; sg < 4; sg++) {
        dot[sp * 4 + sg] += p[sp].x * g[sg].x + p[sp].y * g[sg].y +
                            p[sp].z * g[sg].z + p[sp].w * g[sg].w;
      }
    }
  }

  // Block reduction: wave shuffle -> LDS -> 24 atomics
  __shared__ float red[24][4];
  const int lane = tid & 63;
  const int wave = tid >> 6;
#pragma unroll
  for (int k = 0; k < 24; k++) {
    float v = (k < 16) ? dot[k] : ((k < 20) ? pn[k - 16] : gn[k - 20]);
#pragma unroll
    for (int off = 32; off > 0; off >>= 1) v += __shfl_down(v, off, 64);
    if (lane == 0) red[k][wave] = v;
  }
  __syncthreads();
  if (tid < 24) {
    float s = red[tid][0] + red[tid][1] + red[tid][2] + red[tid][3];
    atomicAdd(&ws[b * 24 + tid], s);
  }
}

__global__ __launch_bounds__(64) void finalize_kernel(const float* __restrict__ ws,
                                                      float* __restrict__ out) {
  const int tid = threadIdx.x;
  float local = 0.f;
  if (tid < B) {
    const float* w = ws + tid * 24;
    float dist[4][4], dcur[4][4];
#pragma unroll
    for (int r = 0; r < 4; r++) {
#pragma unroll
      for (int c = 0; c < 4; c++) {
        float d2 = w[16 + r] + w[20 + c] - 2.0f * w[r * 4 + c];
        float dd = sqrtf(fmaxf(d2, 0.0f));
        dist[r][c] = dd;
        dcur[r][c] = dd;
      }
    }
    int match[4] = {0, 0, 0, 0};
    for (int it = 0; it < 4; ++it) {
      // row-major first-occurrence argmin (matches jnp.argmin on flattened)
      float best = INFINITY;
      int bm = 0;
      for (int r = 0; r < 4; r++)
        for (int c = 0; c < 4; c++) {
          float v = dcur[r][c];
          if (v < best) { best = v; bm = r * 4 + c; }
        }
      const int r = bm >> 2, c = bm & 3;
      match[r] = c;
      for (int k = 0; k < 4; k++) { dcur[r][k] = INFINITY; dcur[k][c] = INFINITY; }
    }
#pragma unroll
    for (int r = 0; r < 4; r++) local += dist[r][match[r]];
  }
#pragma unroll
  for (int off = 32; off > 0; off >>= 1) local += __shfl_down(local, off, 64);
  if (tid == 0) out[0] = local;
}

extern "C" void kernel_launch(void* const* d_in, const int* in_sizes, int n_in,
                              void* d_out, int out_size, void* d_ws, size_t ws_size,
                              hipStream_t stream) {
  const float* preds = (const float*)d_in[0];  // [S,T,B,D]
  const float* gts = (const float*)d_in[1];    // [S,B,T,D]
  float* ws = (float*)d_ws;                    // B*24 floats of accumulators

  hipMemsetAsync(d_ws, 0, B * 24 * sizeof(float), stream);
  partial_kernel<<<dim3(B * CHUNKS), dim3(THREADS), 0, stream>>>(preds, gts, ws);
  finalize_kernel<<<dim3(1), dim3(64), 0, stream>>>(ws, (float*)d_out);
}

// Round 2
// 155.721 us; speedup vs baseline: 1.0038x; 1.0038x over previous
//
#include <hip/hip_runtime.h>

// Problem constants (from reference)
#define S 4
#define T 512
#define B 16
#define D 512
#define L (T * D)            // 262144 floats per (b,s) signal
#define SSTRIDE (T * B * D)  // 4194304 floats between sources (both tensors)

#define CHUNKS 64
#define THREADS 256
#define VEC_PER_CHUNK (L / 4 / CHUNKS)   // 1024 float4 per chunk
#define ITERS (VEC_PER_CHUNK / THREADS)  // 4 iterations per thread

// Per-iter pointer steps in float4 units:
//   i advances by THREADS*4 = 1024 floats -> t advances by 2, d unchanged.
#define PSTEP (2 * B * D / 4)  // 4096 float4
#define GSTEP (THREADS)        // 256  float4
#define SOFF (SSTRIDE / 4)     // float4 stride between sources

// preds: [S,T,B,D] -> idx = s*SSTRIDE + t*(B*D) + b*D + d
// gts:   [S,B,T,D] -> idx = s*SSTRIDE + b*L + (t*D + d)
//
// ws layout per batch b (24 floats): [0..15] dot[s_p*4+s_g], [16..19] pn[s], [20..23] gn[s]

__global__ __launch_bounds__(THREADS) void partial_kernel(
    const float* __restrict__ preds, const float* __restrict__ gts,
    float* __restrict__ ws) {
  const int b = blockIdx.x & (B - 1);
  const int chunk = blockIdx.x >> 4;
  const int tid = threadIdx.x;

  const int i0 = (chunk * VEC_PER_CHUNK + tid) * 4;  // element index in L
  const int t0 = i0 >> 9;
  const int d0 = i0 & 511;

  const float4* pp = reinterpret_cast<const float4*>(preds) +
                     (((size_t)t0 * (B * D) + (size_t)b * D + d0) >> 2);
  const float4* gp = reinterpret_cast<const float4*>(gts) +
                     (((size_t)b * L + i0) >> 2);

  float dot[16], pn[4], gn[4];
#pragma unroll
  for (int k = 0; k < 16; k++) dot[k] = 0.f;
#pragma unroll
  for (int k = 0; k < 4; k++) { pn[k] = 0.f; gn[k] = 0.f; }

  float4 pb[2][4], gb[2][4];

  // Prologue: issue iter-0 loads
#pragma unroll
  for (int s = 0; s < 4; s++) pb[0][s] = pp[(size_t)s * SOFF];
#pragma unroll
  for (int s = 0; s < 4; s++) gb[0][s] = gp[(size_t)s * SOFF];

#pragma unroll
  for (int it = 0; it < ITERS; ++it) {
    const int cb = it & 1;
    const int nb = cb ^ 1;
    // Issue next iteration's loads BEFORE consuming current buffer, so the
    // compiler's s_waitcnt for the compute leaves the prefetch in flight.
    if (it + 1 < ITERS) {
      const float4* pn_ptr = pp + (size_t)(it + 1) * PSTEP;
      const float4* gn_ptr = gp + (size_t)(it + 1) * GSTEP;
#pragma unroll
      for (int s = 0; s < 4; s++) pb[nb][s] = pn_ptr[(size_t)s * SOFF];
#pragma unroll
      for (int s = 0; s < 4; s++) gb[nb][s] = gn_ptr[(size_t)s * SOFF];
    }

#pragma unroll
    for (int s = 0; s < 4; s++) {
      const float4 p = pb[cb][s];
      const float4 g = gb[cb][s];
      pn[s] += p.x * p.x + p.y * p.y + p.z * p.z + p.w * p.w;
      gn[s] += g.x * g.x + g.y * g.y + g.z * g.z + g.w * g.w;
    }
#pragma unroll
    for (int sp = 0; sp < 4; sp++) {
      const float4 p = pb[cb][sp];
#pragma unroll
      for (int sg = 0; sg < 4; sg++) {
        const float4 g = gb[cb][sg];
        dot[sp * 4 + sg] += p.x * g.x + p.y * g.y + p.z * g.z + p.w * g.w;
      }
    }
  }

  // Block reduction: wave shuffle -> LDS -> 24 atomics
  __shared__ float red[24][4];
  const int lane = tid & 63;
  const int wave = tid >> 6;
#pragma unroll
  for (int k = 0; k < 24; k++) {
    float v = (k < 16) ? dot[k] : ((k < 20) ? pn[k - 16] : gn[k - 20]);
#pragma unroll
    for (int off = 32; off > 0; off >>= 1) v += __shfl_down(v, off, 64);
    if (lane == 0) red[k][wave] = v;
  }
  __syncthreads();
  if (tid < 24) {
    float s = red[tid][0] + red[tid][1] + red[tid][2] + red[tid][3];
    atomicAdd(&ws[b * 24 + tid], s);
  }
}

__global__ __launch_bounds__(64) void finalize_kernel(const float* __restrict__ ws,
                                                      float* __restrict__ out) {
  const int tid = threadIdx.x;
  float local = 0.f;
  if (tid < B) {
    const float* w = ws + tid * 24;
    float dist[4][4], dcur[4][4];
#pragma unroll
    for (int r = 0; r < 4; r++) {
#pragma unroll
      for (int c = 0; c < 4; c++) {
        float d2 = w[16 + r] + w[20 + c] - 2.0f * w[r * 4 + c];
        float dd = sqrtf(fmaxf(d2, 0.0f));
        dist[r][c] = dd;
        dcur[r][c] = dd;
      }
    }
    int match[4] = {0, 0, 0, 0};
    for (int it = 0; it < 4; ++it) {
      // row-major first-occurrence argmin (matches jnp.argmin on flattened)
      float best = INFINITY;
      int bm = 0;
      for (int r = 0; r < 4; r++)
        for (int c = 0; c < 4; c++) {
          float v = dcur[r][c];
          if (v < best) { best = v; bm = r * 4 + c; }
        }
      const int r = bm >> 2, c = bm & 3;
      match[r] = c;
      for (int k = 0; k < 4; k++) { dcur[r][k] = INFINITY; dcur[k][c] = INFINITY; }
    }
#pragma unroll
    for (int r = 0; r < 4; r++) local += dist[r][match[r]];
  }
#pragma unroll
  for (int off = 32; off > 0; off >>= 1) local += __shfl_down(local, off, 64);
  if (tid == 0) out[0] = local;
}

extern "C" void kernel_launch(void* const* d_in, const int* in_sizes, int n_in,
                              void* d_out, int out_size, void* d_ws, size_t ws_size,
                              hipStream_t stream) {
  const float* preds = (const float*)d_in[0];  // [S,T,B,D]
  const float* gts = (const float*)d_in[1];    // [S,B,T,D]
  float* ws = (float*)d_ws;                    // B*24 floats of accumulators

  hipMemsetAsync(d_ws, 0, B * 24 * sizeof(float), stream);
  partial_kernel<<<dim3(B * CHUNKS), dim3(THREADS), 0, stream>>>(preds, gts, ws);
  finalize_kernel<<<dim3(1), dim3(64), 0, stream>>>(ws, (float*)d_out);
}

// Round 3
// 155.333 us; speedup vs baseline: 1.0063x; 1.0025x over previous
//
#include <hip/hip_runtime.h>

// Problem constants (from reference)
#define S 4
#define T 512
#define B 16
#define D 512
#define L (T * D)            // 262144 floats per (b,s) signal
#define SSTRIDE (T * B * D)  // 4194304 floats between sources (both tensors)

#define CHUNKS 128
#define THREADS 256
#define VEC_PER_CHUNK (L / 4 / CHUNKS)   // 512 float4 per chunk
#define ITERS (VEC_PER_CHUNK / THREADS)  // 2 iterations per thread

#define SOFF (SSTRIDE / 4)  // float4 stride between sources

// preds: [S,T,B,D] -> idx = s*SSTRIDE + t*(B*D) + b*D + d
// gts:   [S,B,T,D] -> idx = s*SSTRIDE + b*L + (t*D + d)
//
// ws layout per batch b (24 floats): [0..15] dot[s_p*4+s_g], [16..19] pn[s], [20..23] gn[s]

__global__ __launch_bounds__(THREADS) void partial_kernel(
    const float* __restrict__ preds, const float* __restrict__ gts,
    float* __restrict__ ws) {
  const int b = blockIdx.x & (B - 1);
  const int chunk = blockIdx.x >> 4;
  const int tid = threadIdx.x;

  float dot[16], pn[4], gn[4];
#pragma unroll
  for (int k = 0; k < 16; k++) dot[k] = 0.f;
#pragma unroll
  for (int k = 0; k < 4; k++) { pn[k] = 0.f; gn[k] = 0.f; }

#pragma unroll
  for (int it = 0; it < ITERS; ++it) {
    const int ivec = chunk * VEC_PER_CHUNK + it * THREADS + tid;
    const int i = ivec * 4;  // element index within L
    const int t = i >> 9;    // i / 512
    const int d = i & 511;   // i % 512

    const float4* pp =
        reinterpret_cast<const float4*>(preds + (size_t)t * (B * D) + (size_t)b * D + d);
    const float4* gp = reinterpret_cast<const float4*>(gts + (size_t)b * L + i);

    float4 p[4], g[4];
#pragma unroll
    for (int s = 0; s < 4; s++) p[s] = pp[(size_t)s * SOFF];
#pragma unroll
    for (int s = 0; s < 4; s++) g[s] = gp[(size_t)s * SOFF];

#pragma unroll
    for (int s = 0; s < 4; s++) {
      pn[s] += p[s].x * p[s].x + p[s].y * p[s].y + p[s].z * p[s].z + p[s].w * p[s].w;
      gn[s] += g[s].x * g[s].x + g[s].y * g[s].y + g[s].z * g[s].z + g[s].w * g[s].w;
    }
#pragma unroll
    for (int sp = 0; sp < 4; sp++) {
#pragma unroll
      for (int sg = 0; sg < 4; sg++) {
        dot[sp * 4 + sg] += p[sp].x * g[sg].x + p[sp].y * g[sg].y +
                            p[sp].z * g[sg].z + p[sp].w * g[sg].w;
      }
    }
  }

  // Block reduction: wave shuffle -> LDS -> 24 atomics
  __shared__ float red[24][4];
  const int lane = tid & 63;
  const int wave = tid >> 6;
#pragma unroll
  for (int k = 0; k < 24; k++) {
    float v = (k < 16) ? dot[k] : ((k < 20) ? pn[k - 16] : gn[k - 20]);
#pragma unroll
    for (int off = 32; off > 0; off >>= 1) v += __shfl_down(v, off, 64);
    if (lane == 0) red[k][wave] = v;
  }
  __syncthreads();
  if (tid < 24) {
    float s = red[tid][0] + red[tid][1] + red[tid][2] + red[tid][3];
    atomicAdd(&ws[b * 24 + tid], s);
  }
}

__global__ __launch_bounds__(64) void finalize_kernel(const float* __restrict__ ws,
                                                      float* __restrict__ out) {
  const int tid = threadIdx.x;
  float local = 0.f;
  if (tid < B) {
    const float* w = ws + tid * 24;
    float dist[4][4], dcur[4][4];
#pragma unroll
    for (int r = 0; r < 4; r++) {
#pragma unroll
      for (int c = 0; c < 4; c++) {
        float d2 = w[16 + r] + w[20 + c] - 2.0f * w[r * 4 + c];
        float dd = sqrtf(fmaxf(d2, 0.0f));
        dist[r][c] = dd;
        dcur[r][c] = dd;
      }
    }
    int match[4] = {0, 0, 0, 0};
    for (int it = 0; it < 4; ++it) {
      // row-major first-occurrence argmin (matches jnp.argmin on flattened)
      float best = INFINITY;
      int bm = 0;
      for (int r = 0; r < 4; r++)
        for (int c = 0; c < 4; c++) {
          float v = dcur[r][c];
          if (v < best) { best = v; bm = r * 4 + c; }
        }
      const int r = bm >> 2, c = bm & 3;
      match[r] = c;
      for (int k = 0; k < 4; k++) { dcur[r][k] = INFINITY; dcur[k][c] = INFINITY; }
    }
#pragma unroll
    for (int r = 0; r < 4; r++) local += dist[r][match[r]];
  }
#pragma unroll
  for (int off = 32; off > 0; off >>= 1) local += __shfl_down(local, off, 64);
  if (tid == 0) out[0] = local;
}

extern "C" void kernel_launch(void* const* d_in, const int* in_sizes, int n_in,
                              void* d_out, int out_size, void* d_ws, size_t ws_size,
                              hipStream_t stream) {
  const float* preds = (const float*)d_in[0];  // [S,T,B,D]
  const float* gts = (const float*)d_in[1];    // [S,B,T,D]
  float* ws = (float*)d_ws;                    // B*24 floats of accumulators

  hipMemsetAsync(d_ws, 0, B * 24 * sizeof(float), stream);
  partial_kernel<<<dim3(B * CHUNKS), dim3(THREADS), 0, stream>>>(preds, gts, ws);
  finalize_kernel<<<dim3(1), dim3(64), 0, stream>>>(ws, (float*)d_out);
}